// Round 8
// baseline (317.819 us; speedup 1.0000x reference)
//
#include <hip/hip_runtime.h>
#include <stdint.h>

#define N_NODES 50000
#define N_EDGES 800000
#define HID 128
#define NWG_E (N_EDGES / 128)      // 6250 edge blocks
#define XQ (NWG_E / 8)             // 781
#define XR (NWG_E % 8)             // 2
#define SCAN_B 196                 // 196*256 = 50176 >= N_NODES

#define ENC_NEG_INF 0x007FFFFFu   // enc(-inf)

typedef short short8 __attribute__((ext_vector_type(8)));
typedef float f32x4 __attribute__((ext_vector_type(4)));

__device__ __forceinline__ unsigned enc_f32(float f) {
    unsigned u = __float_as_uint(f);
    return (u & 0x80000000u) ? ~u : (u | 0x80000000u);
}
__device__ __forceinline__ float dec_f32(unsigned e) {
    unsigned u = (e & 0x80000000u) ? (e & 0x7FFFFFFFu) : ~e;
    return __uint_as_float(u);
}
__device__ __forceinline__ unsigned short f2bf(float f) {
    unsigned u = __float_as_uint(f);
    unsigned r = (u + 0x7fffu + ((u >> 16) & 1u)) >> 16;
    return (unsigned short)r;
}
__device__ __forceinline__ float bf2f(unsigned short h) {
    return __uint_as_float(((unsigned)h) << 16);
}

// ---------------- utility kernels ----------------

__global__ void fill_u32(unsigned* __restrict__ p, int n, unsigned v) {
    int i = blockIdx.x * blockDim.x + threadIdx.x;
    int stride = gridDim.x * blockDim.x;
    for (; i < n; i += stride) p[i] = v;
}

// Build combined weight WC[K][256]: cols 0..127 = Wtop - Wbot, 128..255 = Wbot
__global__ void prep_wcat(const float* __restrict__ W, int K, float* __restrict__ WC) {
    int idx = blockIdx.x * 256 + threadIdx.x;
    if (idx >= K * 256) return;
    int k = idx >> 8, c = idx & 255;
    float v;
    if (c < 128) v = W[k * 128 + c] - W[(k + K) * 128 + c];
    else         v = W[(k + K) * 128 + (c - 128)];
    WC[idx] = v;
}

// Wb[128][128] -> MFMA B-frag hi plane, HALF-MAJOR tile order:
// tile t = h*16 + kt*4 + ntl (h = n-half, nt = 4h+ntl), 512 shorts per tile.
__global__ void prep_wfrag(const float* __restrict__ Wb, unsigned short* __restrict__ Wg) {
    int idx = blockIdx.x * 256 + threadIdx.x;   // 0..16383
    int j = idx & 7, l = (idx >> 3) & 63, t = idx >> 9;
    int h = t >> 4, kt = (t >> 2) & 3, ntl = t & 3;
    int nt = 4 * h + ntl;
    int k = 32 * kt + 8 * (l >> 4) + j;
    int n = 16 * nt + (l & 15);
    Wg[idx] = f2bf(Wb[k * 128 + n]);
}

// WC[K][256] -> MFMA B-frag layout (N=256, 16 n-tiles), hi plane then lo plane (K*256 each)
__global__ void prep_wfrag256(const float* __restrict__ WC, int K, unsigned short* __restrict__ Wg) {
    int idx = blockIdx.x * 256 + threadIdx.x;
    if (idx >= K * 256) return;
    int j = idx & 7, l = (idx >> 3) & 63, nt = (idx >> 9) & 15, kt = idx >> 13;
    int k = 32 * kt + 8 * (l >> 4) + j;
    int n = 16 * nt + (l & 15);
    float v = WC[k * 256 + n];
    unsigned short hi = f2bf(v);
    Wg[idx] = hi;
    Wg[K * 256 + idx] = f2bf(v - bf2f(hi));
}

// final: encoded u32 -> decoded float + bias; empty segment -> 0
__global__ void out_decode(unsigned* __restrict__ p, const float* __restrict__ bias, int n) {
    int i = blockIdx.x * blockDim.x + threadIdx.x;
    int stride = gridDim.x * blockDim.x;
    for (; i < n; i += stride) {
        unsigned e = p[i];
        float f = (e == ENC_NEG_INF) ? 0.0f : dec_f32(e) + bias[i & 127];
        ((float*)p)[i] = f;
    }
}

// ---------------- sort-by-dst (counting sort, multi-block scan) ----------------

__global__ void hist_dst(const int* __restrict__ dst, unsigned* __restrict__ count) {
    int i = blockIdx.x * blockDim.x + threadIdx.x;
    if (i < N_EDGES) atomicAdd(&count[dst[i]], 1u);
}

__global__ __launch_bounds__(256) void scan_p1(const unsigned* __restrict__ count,
                                               unsigned* __restrict__ bsum) {
    __shared__ unsigned s[256];
    int t = threadIdx.x;
    int i = blockIdx.x * 256 + t;
    s[t] = (i < N_NODES) ? count[i] : 0u;
    __syncthreads();
    for (int off = 128; off > 0; off >>= 1) {
        if (t < off) s[t] += s[t + off];
        __syncthreads();
    }
    if (t == 0) bsum[blockIdx.x] = s[0];
}

__global__ __launch_bounds__(256) void scan_p2(unsigned* __restrict__ bsum) {
    __shared__ unsigned s[256];
    int t = threadIdx.x;
    unsigned v = (t < SCAN_B) ? bsum[t] : 0u;
    s[t] = v;
    __syncthreads();
    for (int off = 1; off < 256; off <<= 1) {
        unsigned x = (t >= off) ? s[t - off] : 0u;
        __syncthreads();
        s[t] += x;
        __syncthreads();
    }
    if (t < SCAN_B) bsum[t] = s[t] - v;   // exclusive
}

__global__ __launch_bounds__(256) void scan_p3(const unsigned* __restrict__ count,
                                               const unsigned* __restrict__ bsum,
                                               unsigned* __restrict__ cursor) {
    __shared__ unsigned s[256];
    int t = threadIdx.x;
    int i = blockIdx.x * 256 + t;
    unsigned v = (i < N_NODES) ? count[i] : 0u;
    s[t] = v;
    __syncthreads();
    for (int off = 1; off < 256; off <<= 1) {
        unsigned x = (t >= off) ? s[t - off] : 0u;
        __syncthreads();
        s[t] += x;
        __syncthreads();
    }
    if (i < N_NODES) cursor[i] = bsum[blockIdx.x] + s[t] - v;
}

__global__ void scatter_edges(const int* __restrict__ src, const int* __restrict__ dst,
                              unsigned* __restrict__ cursor,
                              int* __restrict__ ssrc, int* __restrict__ sdst) {
    int i = blockIdx.x * blockDim.x + threadIdx.x;
    if (i < N_EDGES) {
        int d = dst[i];
        unsigned p = atomicAdd(&cursor[d], 1u);
        ssrc[p] = src[i];
        sdst[p] = d;
    }
}

// ---------------- MFMA node GEMM: C[M][256](bf16) = op(A)[M][K] @ WC[K][256] ----------------
template<int DEC, int KT>
__global__ __launch_bounds__(256, 2) void gemm_uv_mfma(
        const void* __restrict__ A_,
        const unsigned short* __restrict__ Wg,   // frag layout, hi|lo planes (K*256 shorts each)
        const float* __restrict__ bprev,         // DEC=1 bias (pre-relu); unused otherwise
        const float* __restrict__ bu,            // U-col bias, applied when by==0
        unsigned short* __restrict__ C,          // [M][256] bf16
        int M) {
    __shared__ char lds[KT * 8192];
    const int K = 32 * KT;
    int tid = threadIdx.x;
    int bx = blockIdx.x, by = blockIdx.y;
    int r0 = bx * 128;
    int w = tid >> 6, l = tid & 63;
    int q = l >> 4, m = l & 15;

    short8 ahi[2][KT];
#pragma unroll
    for (int mt = 0; mt < 2; ++mt) {
        int row = r0 + 32 * w + 16 * mt + m;
        bool ok = row < M;
#pragma unroll
        for (int kt = 0; kt < KT; ++kt) {
            float av[8] = {0.f, 0.f, 0.f, 0.f, 0.f, 0.f, 0.f, 0.f};
            if (ok) {
                if (DEC) {
                    const unsigned* Ar = (const unsigned*)A_ + (size_t)row * K + 32 * kt + 8 * q;
                    uint4 x0 = *(const uint4*)Ar;
                    uint4 x1 = *(const uint4*)(Ar + 4);
                    float4 g0 = *(const float4*)&bprev[32 * kt + 8 * q];
                    float4 g1 = *(const float4*)&bprev[32 * kt + 8 * q + 4];
                    av[0] = fmaxf(dec_f32(x0.x) + g0.x, 0.f);
                    av[1] = fmaxf(dec_f32(x0.y) + g0.y, 0.f);
                    av[2] = fmaxf(dec_f32(x0.z) + g0.z, 0.f);
                    av[3] = fmaxf(dec_f32(x0.w) + g0.w, 0.f);
                    av[4] = fmaxf(dec_f32(x1.x) + g1.x, 0.f);
                    av[5] = fmaxf(dec_f32(x1.y) + g1.y, 0.f);
                    av[6] = fmaxf(dec_f32(x1.z) + g1.z, 0.f);
                    av[7] = fmaxf(dec_f32(x1.w) + g1.w, 0.f);
                } else {
                    const float* Ar = (const float*)A_ + (size_t)row * K + 32 * kt + 8 * q;
                    float4 f0 = *(const float4*)Ar;
                    float4 f1 = *(const float4*)(Ar + 4);
                    av[0] = f0.x; av[1] = f0.y; av[2] = f0.z; av[3] = f0.w;
                    av[4] = f1.x; av[5] = f1.y; av[6] = f1.z; av[7] = f1.w;
                }
            }
            short8 hi;
#pragma unroll
            for (int j = 0; j < 8; ++j) hi[j] = (short)f2bf(av[j]);
            ahi[mt][kt] = hi;
        }
    }

    f32x4 acc[2][8];
#pragma unroll
    for (int mt = 0; mt < 2; ++mt)
#pragma unroll
        for (int nt = 0; nt < 8; ++nt)
            acc[mt][nt] = (f32x4){0.f, 0.f, 0.f, 0.f};

    const short8* bfr = (const short8*)lds;

#pragma unroll
    for (int pl = 0; pl < 2; ++pl) {
        if (pl) __syncthreads();
        {
            const float4* s4 = (const float4*)Wg + (size_t)pl * (K * 32);
            float4* d4 = (float4*)lds;
#pragma unroll
            for (int it = 0; it < 2 * KT; ++it) {
                int f = 256 * it + tid;
                int tl = f >> 6, fin = f & 63;
                int tg = (tl >> 3) * 16 + 8 * by + (tl & 7);
                d4[f] = s4[tg * 64 + fin];
            }
        }
        __syncthreads();
#pragma unroll
        for (int nt = 0; nt < 8; ++nt)
#pragma unroll
            for (int kt = 0; kt < KT; ++kt) {
                short8 b = bfr[(kt * 8 + nt) * 64 + l];
                acc[0][nt] = __builtin_amdgcn_mfma_f32_16x16x32_bf16(ahi[0][kt], b, acc[0][nt], 0, 0, 0);
                acc[1][nt] = __builtin_amdgcn_mfma_f32_16x16x32_bf16(ahi[1][kt], b, acc[1][nt], 0, 0, 0);
            }
    }

#pragma unroll
    for (int nt = 0; nt < 8; ++nt) {
        float bias = (by == 0) ? bu[16 * nt + m] : 0.f;
#pragma unroll
        for (int mt = 0; mt < 2; ++mt) {
            int rowb = r0 + 32 * w + 16 * mt + 4 * q;
#pragma unroll
            for (int r = 0; r < 4; ++r) {
                int row = rowb + r;
                if (row < M)
                    C[(size_t)row * 256 + 128 * by + 16 * nt + m] = f2bf(acc[mt][nt][r] + bias);
            }
        }
    }
}

// ---------------- MFMA edge MLP + segmented max-aggregate ----------------
// 128 sorted edges / block, 4 waves, 2 n-passes (acc 32 AGPR), 5 blocks/CU.
__global__ __launch_bounds__(256, 5) void edge_mlp_mfma(
        const unsigned short* __restrict__ UV, // [N][256] bf16: U 0..127 (incl. ba), V 128..255
        const unsigned short* __restrict__ Wg, // hi plane, half-major tiles (16384 shorts)
        const int* __restrict__ ssrc,
        const int* __restrict__ sdst,
        unsigned* __restrict__ AGG) {          // [N][128] encoded (bb added downstream)
    __shared__ char lds[17408];                // union: W half (16KB) | M2[128][34] f32
    __shared__ int sdst_s[128];
    int tid = threadIdx.x;
    // bijective XCD-chunked swizzle
    int orig = blockIdx.x;
    int xcd = orig & 7, ii = orig >> 3;
    int wg = (xcd < XR) ? xcd * (XQ + 1) + ii : XR * (XQ + 1) + (xcd - XR) * XQ + ii;
    int e0 = wg * 128;
    int w = tid >> 6, l = tid & 63;
    int q = l >> 4, m = l & 15;

    if (tid < 128) sdst_s[tid] = sdst[e0 + tid];

    // A-build: prefetch indices, then one 8-load batch per edge (MLP)
    short8 ahi[2][4];
    {
        int eA = e0 + 32 * w + m;
        int d0 = sdst[eA], s0 = ssrc[eA];
        int d1 = sdst[eA + 16], s1 = ssrc[eA + 16];
#pragma unroll
        for (int mt = 0; mt < 2; ++mt) {
            int d = mt ? d1 : d0, s = mt ? s1 : s0;
            const short8* Ud = (const short8*)&UV[(size_t)d * 256];
            const short8* Vs = (const short8*)&UV[(size_t)s * 256 + 128];
            short8 u0 = Ud[q],      u1 = Ud[4 + q],  u2 = Ud[8 + q],  u3 = Ud[12 + q];
            short8 v0 = Vs[q],      v1 = Vs[4 + q],  v2 = Vs[8 + q],  v3 = Vs[12 + q];
            short8 ub[4] = {u0, u1, u2, u3};
            short8 vb[4] = {v0, v1, v2, v3};
#pragma unroll
            for (int kt = 0; kt < 4; ++kt) {
                short8 hi;
#pragma unroll
                for (int j = 0; j < 8; ++j) {
                    float t = bf2f((unsigned short)ub[kt][j]) + bf2f((unsigned short)vb[kt][j]);
                    hi[j] = (short)f2bf(fmaxf(t, 0.f));
                }
                ahi[mt][kt] = hi;
            }
        }
    }

    const short8* bfr = (const short8*)lds;
    float* M2 = (float*)lds;
    f32x4 acc[2][4];

#pragma unroll
    for (int h = 0; h < 2; ++h) {
        __syncthreads();   // prior pass's M2 readers done (or first entry)
        // stage W half h (16KB)
        {
            const float4* s4 = (const float4*)Wg + h * 1024;
            float4* d4 = (float4*)lds;
#pragma unroll
            for (int i = 0; i < 4; ++i) d4[tid + 256 * i] = s4[tid + 256 * i];
        }
        __syncthreads();
#pragma unroll
        for (int mt = 0; mt < 2; ++mt)
#pragma unroll
            for (int ntl = 0; ntl < 4; ++ntl)
                acc[mt][ntl] = (f32x4){0.f, 0.f, 0.f, 0.f};
#pragma unroll
        for (int ntl = 0; ntl < 4; ++ntl)
#pragma unroll
            for (int kt = 0; kt < 4; ++kt) {
                short8 b = bfr[(kt * 4 + ntl) * 64 + l];
                acc[0][ntl] = __builtin_amdgcn_mfma_f32_16x16x32_bf16(ahi[0][kt], b, acc[0][ntl], 0, 0, 0);
                acc[1][ntl] = __builtin_amdgcn_mfma_f32_16x16x32_bf16(ahi[1][kt], b, acc[1][ntl], 0, 0, 0);
            }

        // two 32-col chunks per pass
#pragma unroll
        for (int cn = 0; cn < 2; ++cn) {
            __syncthreads();   // b-reads (cn=0) / prev segmax reads (cn=1) done
#pragma unroll
            for (int nt2 = 0; nt2 < 2; ++nt2) {
                int ntl = 2 * cn + nt2;
#pragma unroll
                for (int mt = 0; mt < 2; ++mt)
#pragma unroll
                    for (int r = 0; r < 4; ++r)
                        M2[(32 * w + 16 * mt + 4 * q + r) * 34 + 16 * nt2 + m] = acc[mt][ntl][r];
            }
            __syncthreads();
            {
                int c = tid & 31, g = tid >> 5;
                int eb = 16 * g;
                int cur = sdst_s[eb];
                float mx = -3.402823466e38f;
                for (int e2 = eb; e2 < eb + 16; ++e2) {
                    int de = sdst_s[e2];
                    if (de != cur) {
                        atomicMax(&AGG[(size_t)cur * 128 + 64 * h + 32 * cn + c], enc_f32(mx));
                        cur = de;
                        mx = -3.402823466e38f;
                    }
                    mx = fmaxf(mx, M2[e2 * 34 + c]);
                }
                atomicMax(&AGG[(size_t)cur * 128 + 64 * h + 32 * cn + c], enc_f32(mx));
            }
        }
    }
}

// ---------------- launch ----------------

extern "C" void kernel_launch(void* const* d_in, const int* in_sizes, int n_in,
                              void* d_out, int out_size, void* d_ws, size_t ws_size,
                              hipStream_t stream) {
    const float* x   = (const float*)d_in[0];
    const int*   ei  = (const int*)d_in[1];
    const float* W1a = (const float*)d_in[2];
    const float* b1a = (const float*)d_in[3];
    const float* W1b = (const float*)d_in[4];
    const float* b1b = (const float*)d_in[5];
    const float* W2a = (const float*)d_in[6];
    const float* b2a = (const float*)d_in[7];
    const float* W2b = (const float*)d_in[8];
    const float* b2b = (const float*)d_in[9];
    const int* src = ei;
    const int* dst = ei + N_EDGES;

    char* ws = (char*)d_ws;
    unsigned short* UV    = (unsigned short*)ws;                 // 25.6 MB (bf16)
    unsigned*       AGG1  = (unsigned*)(ws + 25600000);          // 25.6 MB
    int*            ssrc  = (int*)(ws + 51200000);               // 3.2 MB
    int*            sdst  = (int*)(ws + 54400000);               // 3.2 MB
    unsigned*       count = (unsigned*)(ws + 57600000);          // 200 KB
    unsigned*       cursor= (unsigned*)(ws + 57800000);          // 200 KB
    unsigned short* Wg1   = (unsigned short*)(ws + 58000000);    // 32 KB used (hi, half-major)
    unsigned short* Wg2   = (unsigned short*)(ws + 58065536);    // 32 KB used
    float*          WC1   = (float*)(ws + 58131072);             // 64 KB
    float*          WC2   = (float*)(ws + 58196608);             // 128 KB
    unsigned short* WCg1  = (unsigned short*)(ws + 58327680);    // 64 KB (frag hi|lo)
    unsigned short* WCg2  = (unsigned short*)(ws + 58393216);    // 128 KB
    unsigned*       bsum  = (unsigned*)(ws + 58655744);          // 1 KB

    const int NH = N_NODES * HID;   // 6.4M

    prep_wcat<<<64, 256, 0, stream>>>(W1a, 64, WC1);
    prep_wcat<<<128, 256, 0, stream>>>(W2a, 128, WC2);
    prep_wfrag<<<64, 256, 0, stream>>>(W1b, Wg1);
    prep_wfrag<<<64, 256, 0, stream>>>(W2b, Wg2);
    prep_wfrag256<<<64, 256, 0, stream>>>(WC1, 64, WCg1);
    prep_wfrag256<<<128, 256, 0, stream>>>(WC2, 128, WCg2);
    fill_u32<<<2048, 256, 0, stream>>>(AGG1, NH, ENC_NEG_INF);
    fill_u32<<<2048, 256, 0, stream>>>((unsigned*)d_out, NH, ENC_NEG_INF);
    fill_u32<<<196, 256, 0, stream>>>(count, N_NODES, 0u);

    // counting sort of edges by dst (max is order-independent -> deterministic)
    hist_dst<<<3125, 256, 0, stream>>>(dst, count);
    scan_p1<<<SCAN_B, 256, 0, stream>>>(count, bsum);
    scan_p2<<<1, 256, 0, stream>>>(bsum);
    scan_p3<<<SCAN_B, 256, 0, stream>>>(count, bsum, cursor);
    scatter_edges<<<3125, 256, 0, stream>>>(src, dst, cursor, ssrc, sdst);

    // Layer 1: UV = [x@(W1a_t - W1a_b) + b1a | x@W1a_b]  (bf16, U-bias folded)
    gemm_uv_mfma<0, 2><<<dim3(391, 2), 256, 0, stream>>>(x, WCg1, nullptr, b1a, UV, N_NODES);
    edge_mlp_mfma<<<NWG_E, 256, 0, stream>>>(UV, Wg1, ssrc, sdst, AGG1);

    // Layer 2: H = relu(dec(AGG1) + b1b) fused into A-load
    gemm_uv_mfma<1, 4><<<dim3(391, 2), 256, 0, stream>>>(AGG1, WCg2, b1b, b2a, UV, N_NODES);
    edge_mlp_mfma<<<NWG_E, 256, 0, stream>>>(UV, Wg2, ssrc, sdst, (unsigned*)d_out);
    out_decode<<<2048, 256, 0, stream>>>((unsigned*)d_out, b2b, NH);
}

// Round 9
// 314.867 us; speedup vs baseline: 1.0094x; 1.0094x over previous
//
#include <hip/hip_runtime.h>
#include <stdint.h>

#define N_NODES 50000
#define N_EDGES 800000
#define HID 128
#define NWG_E (N_EDGES / 128)      // 6250 edge blocks
#define XQ (NWG_E / 8)             // 781
#define XR (NWG_E % 8)             // 2
#define SCAN_B 196                 // 196*256 = 50176 >= N_NODES

#define ENC_NEG_INF 0x007FFFFFu   // enc(-inf)

typedef short short8 __attribute__((ext_vector_type(8)));
typedef float f32x4 __attribute__((ext_vector_type(4)));

__device__ __forceinline__ unsigned enc_f32(float f) {
    unsigned u = __float_as_uint(f);
    return (u & 0x80000000u) ? ~u : (u | 0x80000000u);
}
__device__ __forceinline__ float dec_f32(unsigned e) {
    unsigned u = (e & 0x80000000u) ? (e & 0x7FFFFFFFu) : ~e;
    return __uint_as_float(u);
}
__device__ __forceinline__ unsigned short f2bf(float f) {
    unsigned u = __float_as_uint(f);
    unsigned r = (u + 0x7fffu + ((u >> 16) & 1u)) >> 16;
    return (unsigned short)r;
}
__device__ __forceinline__ float bf2f(unsigned short h) {
    return __uint_as_float(((unsigned)h) << 16);
}
__device__ __forceinline__ float wcat_val(const float* __restrict__ W, int K, int k, int n) {
    // combined weight: cols 0..127 = Wtop - Wbot, 128..255 = Wbot
    return (n < 128) ? (W[k * 128 + n] - W[(k + K) * 128 + n]) : W[(k + K) * 128 + (n - 128)];
}

// ---------------- fused setup: W-frag preps + big fills ----------------
__global__ __launch_bounds__(256) void setup(
        const float* __restrict__ W1a, const float* __restrict__ W1b,
        const float* __restrict__ W2a, const float* __restrict__ W2b,
        unsigned short* __restrict__ Wg1, unsigned short* __restrict__ Wg2,
        unsigned short* __restrict__ WCg1, unsigned short* __restrict__ WCg2,
        unsigned* __restrict__ AGG1, unsigned* __restrict__ OUT,
        unsigned* __restrict__ count) {
    int bid = blockIdx.x, tid = threadIdx.x;
    const int NH = N_NODES * HID;

    if (bid < 128) {
        // Wg1/Wg2: Wb[128][128] -> hi-plane frags, HALF-MAJOR tile order
        const float* Wb = (bid < 64) ? W1b : W2b;
        unsigned short* Wg = (bid < 64) ? Wg1 : Wg2;
        int idx = (bid & 63) * 256 + tid;          // 0..16383
        int j = idx & 7, l = (idx >> 3) & 63, t = idx >> 9;
        int h = t >> 4, kt = (t >> 2) & 3, ntl = t & 3;
        int nt = 4 * h + ntl;
        int k = 32 * kt + 8 * (l >> 4) + j;
        int n = 16 * nt + (l & 15);
        Wg[idx] = f2bf(Wb[k * 128 + n]);
    } else if (bid < 192) {
        // WCg1: K=64, idx 0..16383, hi|lo planes
        int idx = (bid - 128) * 256 + tid;
        int j = idx & 7, l = (idx >> 3) & 63, nt = (idx >> 9) & 15, kt = idx >> 13;
        int k = 32 * kt + 8 * (l >> 4) + j;
        int n = 16 * nt + (l & 15);
        float v = wcat_val(W1a, 64, k, n);
        unsigned short hi = f2bf(v);
        WCg1[idx] = hi;
        WCg1[64 * 256 + idx] = f2bf(v - bf2f(hi));
    } else if (bid < 320) {
        // WCg2: K=128, idx 0..32767, hi|lo planes
        int idx = (bid - 192) * 256 + tid;
        int j = idx & 7, l = (idx >> 3) & 63, nt = (idx >> 9) & 15, kt = idx >> 13;
        int k = 32 * kt + 8 * (l >> 4) + j;
        int n = 16 * nt + (l & 15);
        float v = wcat_val(W2a, 128, k, n);
        unsigned short hi = f2bf(v);
        WCg2[idx] = hi;
        WCg2[128 * 256 + idx] = f2bf(v - bf2f(hi));
    }

    // fills: AGG1, OUT (= d_out), count
    int total = 2 * NH + N_NODES;
    for (int i = bid * 256 + tid; i < total; i += gridDim.x * 256) {
        if (i < NH) AGG1[i] = ENC_NEG_INF;
        else if (i < 2 * NH) OUT[i - NH] = ENC_NEG_INF;
        else count[i - 2 * NH] = 0u;
    }
}

// final: encoded u32 -> decoded float + bias; empty segment -> 0
__global__ void out_decode(unsigned* __restrict__ p, const float* __restrict__ bias, int n) {
    int i = blockIdx.x * blockDim.x + threadIdx.x;
    int stride = gridDim.x * blockDim.x;
    for (; i < n; i += stride) {
        unsigned e = p[i];
        float f = (e == ENC_NEG_INF) ? 0.0f : dec_f32(e) + bias[i & 127];
        ((float*)p)[i] = f;
    }
}

// ---------------- sort-by-dst (counting sort, multi-block scan) ----------------

__global__ void hist_dst(const int* __restrict__ dst, unsigned* __restrict__ count) {
    int i = blockIdx.x * blockDim.x + threadIdx.x;
    if (i < N_EDGES) atomicAdd(&count[dst[i]], 1u);
}

__global__ __launch_bounds__(256) void scan_p1(const unsigned* __restrict__ count,
                                               unsigned* __restrict__ bsum) {
    __shared__ unsigned s[256];
    int t = threadIdx.x;
    int i = blockIdx.x * 256 + t;
    s[t] = (i < N_NODES) ? count[i] : 0u;
    __syncthreads();
    for (int off = 128; off > 0; off >>= 1) {
        if (t < off) s[t] += s[t + off];
        __syncthreads();
    }
    if (t == 0) bsum[blockIdx.x] = s[0];
}

__global__ __launch_bounds__(256) void scan_p2(unsigned* __restrict__ bsum) {
    __shared__ unsigned s[256];
    int t = threadIdx.x;
    unsigned v = (t < SCAN_B) ? bsum[t] : 0u;
    s[t] = v;
    __syncthreads();
    for (int off = 1; off < 256; off <<= 1) {
        unsigned x = (t >= off) ? s[t - off] : 0u;
        __syncthreads();
        s[t] += x;
        __syncthreads();
    }
    if (t < SCAN_B) bsum[t] = s[t] - v;   // exclusive
}

__global__ __launch_bounds__(256) void scan_p3(const unsigned* __restrict__ count,
                                               const unsigned* __restrict__ bsum,
                                               unsigned* __restrict__ cursor) {
    __shared__ unsigned s[256];
    int t = threadIdx.x;
    int i = blockIdx.x * 256 + t;
    unsigned v = (i < N_NODES) ? count[i] : 0u;
    s[t] = v;
    __syncthreads();
    for (int off = 1; off < 256; off <<= 1) {
        unsigned x = (t >= off) ? s[t - off] : 0u;
        __syncthreads();
        s[t] += x;
        __syncthreads();
    }
    if (i < N_NODES) cursor[i] = bsum[blockIdx.x] + s[t] - v;
}

__global__ void scatter_edges(const int* __restrict__ src, const int* __restrict__ dst,
                              unsigned* __restrict__ cursor,
                              int* __restrict__ ssrc, int* __restrict__ sdst) {
    int i = blockIdx.x * blockDim.x + threadIdx.x;
    if (i < N_EDGES) {
        int d = dst[i];
        unsigned p = atomicAdd(&cursor[d], 1u);
        ssrc[p] = src[i];
        sdst[p] = d;
    }
}

// ---------------- MFMA node GEMM: C[M][256](bf16) = op(A)[M][K] @ WC[K][256] ----------------
template<int DEC, int KT>
__global__ __launch_bounds__(256, 2) void gemm_uv_mfma(
        const void* __restrict__ A_,
        const unsigned short* __restrict__ Wg,   // frag layout, hi|lo planes (K*256 shorts each)
        const float* __restrict__ bprev,         // DEC=1 bias (pre-relu); unused otherwise
        const float* __restrict__ bu,            // U-col bias, applied when by==0
        unsigned short* __restrict__ C,          // [M][256] bf16
        int M) {
    __shared__ char lds[KT * 8192];
    const int K = 32 * KT;
    int tid = threadIdx.x;
    int bx = blockIdx.x, by = blockIdx.y;
    int r0 = bx * 128;
    int w = tid >> 6, l = tid & 63;
    int q = l >> 4, m = l & 15;

    short8 ahi[2][KT];
#pragma unroll
    for (int mt = 0; mt < 2; ++mt) {
        int row = r0 + 32 * w + 16 * mt + m;
        bool ok = row < M;
#pragma unroll
        for (int kt = 0; kt < KT; ++kt) {
            float av[8] = {0.f, 0.f, 0.f, 0.f, 0.f, 0.f, 0.f, 0.f};
            if (ok) {
                if (DEC) {
                    const unsigned* Ar = (const unsigned*)A_ + (size_t)row * K + 32 * kt + 8 * q;
                    uint4 x0 = *(const uint4*)Ar;
                    uint4 x1 = *(const uint4*)(Ar + 4);
                    float4 g0 = *(const float4*)&bprev[32 * kt + 8 * q];
                    float4 g1 = *(const float4*)&bprev[32 * kt + 8 * q + 4];
                    av[0] = fmaxf(dec_f32(x0.x) + g0.x, 0.f);
                    av[1] = fmaxf(dec_f32(x0.y) + g0.y, 0.f);
                    av[2] = fmaxf(dec_f32(x0.z) + g0.z, 0.f);
                    av[3] = fmaxf(dec_f32(x0.w) + g0.w, 0.f);
                    av[4] = fmaxf(dec_f32(x1.x) + g1.x, 0.f);
                    av[5] = fmaxf(dec_f32(x1.y) + g1.y, 0.f);
                    av[6] = fmaxf(dec_f32(x1.z) + g1.z, 0.f);
                    av[7] = fmaxf(dec_f32(x1.w) + g1.w, 0.f);
                } else {
                    const float* Ar = (const float*)A_ + (size_t)row * K + 32 * kt + 8 * q;
                    float4 f0 = *(const float4*)Ar;
                    float4 f1 = *(const float4*)(Ar + 4);
                    av[0] = f0.x; av[1] = f0.y; av[2] = f0.z; av[3] = f0.w;
                    av[4] = f1.x; av[5] = f1.y; av[6] = f1.z; av[7] = f1.w;
                }
            }
            short8 hi;
#pragma unroll
            for (int j = 0; j < 8; ++j) hi[j] = (short)f2bf(av[j]);
            ahi[mt][kt] = hi;
        }
    }

    f32x4 acc[2][8];
#pragma unroll
    for (int mt = 0; mt < 2; ++mt)
#pragma unroll
        for (int nt = 0; nt < 8; ++nt)
            acc[mt][nt] = (f32x4){0.f, 0.f, 0.f, 0.f};

    const short8* bfr = (const short8*)lds;

#pragma unroll
    for (int pl = 0; pl < 2; ++pl) {
        if (pl) __syncthreads();
        {
            const float4* s4 = (const float4*)Wg + (size_t)pl * (K * 32);
            float4* d4 = (float4*)lds;
#pragma unroll
            for (int it = 0; it < 2 * KT; ++it) {
                int f = 256 * it + tid;
                int tl = f >> 6, fin = f & 63;
                int tg = (tl >> 3) * 16 + 8 * by + (tl & 7);
                d4[f] = s4[tg * 64 + fin];
            }
        }
        __syncthreads();
#pragma unroll
        for (int nt = 0; nt < 8; ++nt)
#pragma unroll
            for (int kt = 0; kt < KT; ++kt) {
                short8 b = bfr[(kt * 8 + nt) * 64 + l];
                acc[0][nt] = __builtin_amdgcn_mfma_f32_16x16x32_bf16(ahi[0][kt], b, acc[0][nt], 0, 0, 0);
                acc[1][nt] = __builtin_amdgcn_mfma_f32_16x16x32_bf16(ahi[1][kt], b, acc[1][nt], 0, 0, 0);
            }
    }

#pragma unroll
    for (int nt = 0; nt < 8; ++nt) {
        float bias = (by == 0) ? bu[16 * nt + m] : 0.f;
#pragma unroll
        for (int mt = 0; mt < 2; ++mt) {
            int rowb = r0 + 32 * w + 16 * mt + 4 * q;
#pragma unroll
            for (int r = 0; r < 4; ++r) {
                int row = rowb + r;
                if (row < M)
                    C[(size_t)row * 256 + 128 * by + 16 * nt + m] = f2bf(acc[mt][nt][r] + bias);
            }
        }
    }
}

// ---------------- MFMA edge MLP + segmented max-aggregate ----------------
// 128 sorted edges / block, 4 waves, 2 n-passes. All 16 gather loads batched
// before conversion (MLP); launch_bounds(256,4) gives the pending-load VGPR room.
__global__ __launch_bounds__(256, 4) void edge_mlp_mfma(
        const unsigned short* __restrict__ UV, // [N][256] bf16: U 0..127 (incl. ba), V 128..255
        const unsigned short* __restrict__ Wg, // hi plane, half-major tiles (16384 shorts)
        const int* __restrict__ ssrc,
        const int* __restrict__ sdst,
        unsigned* __restrict__ AGG) {          // [N][128] encoded (bb added downstream)
    __shared__ char lds[17408];                // union: W half (16KB) | M2[128][34] f32
    __shared__ int sdst_s[128];
    int tid = threadIdx.x;
    // bijective XCD-chunked swizzle
    int orig = blockIdx.x;
    int xcd = orig & 7, ii = orig >> 3;
    int wg = (xcd < XR) ? xcd * (XQ + 1) + ii : XR * (XQ + 1) + (xcd - XR) * XQ + ii;
    int e0 = wg * 128;
    int w = tid >> 6, l = tid & 63;
    int q = l >> 4, m = l & 15;

    if (tid < 128) sdst_s[tid] = sdst[e0 + tid];

    // A-build: issue ALL 16 gather loads, then convert (max loads in flight)
    short8 ahi[2][4];
    {
        int eA = e0 + 32 * w + m;
        int d0 = sdst[eA], s0 = ssrc[eA];
        int d1 = sdst[eA + 16], s1 = ssrc[eA + 16];
        const short8* Ud0 = (const short8*)&UV[(size_t)d0 * 256];
        const short8* Vs0 = (const short8*)&UV[(size_t)s0 * 256 + 128];
        const short8* Ud1 = (const short8*)&UV[(size_t)d1 * 256];
        const short8* Vs1 = (const short8*)&UV[(size_t)s1 * 256 + 128];
        short8 ub[2][4], vb[2][4];
#pragma unroll
        for (int kt = 0; kt < 4; ++kt) {
            ub[0][kt] = Ud0[4 * kt + q];
            vb[0][kt] = Vs0[4 * kt + q];
            ub[1][kt] = Ud1[4 * kt + q];
            vb[1][kt] = Vs1[4 * kt + q];
        }
#pragma unroll
        for (int mt = 0; mt < 2; ++mt)
#pragma unroll
            for (int kt = 0; kt < 4; ++kt) {
                short8 hi;
#pragma unroll
                for (int j = 0; j < 8; ++j) {
                    float t = bf2f((unsigned short)ub[mt][kt][j]) + bf2f((unsigned short)vb[mt][kt][j]);
                    hi[j] = (short)f2bf(fmaxf(t, 0.f));
                }
                ahi[mt][kt] = hi;
            }
    }

    const short8* bfr = (const short8*)lds;
    float* M2 = (float*)lds;
    f32x4 acc[2][4];

#pragma unroll
    for (int h = 0; h < 2; ++h) {
        __syncthreads();   // prior pass's M2 readers done (or first entry)
        // stage W half h (16KB)
        {
            const float4* s4 = (const float4*)Wg + h * 1024;
            float4* d4 = (float4*)lds;
#pragma unroll
            for (int i = 0; i < 4; ++i) d4[tid + 256 * i] = s4[tid + 256 * i];
        }
        __syncthreads();
#pragma unroll
        for (int mt = 0; mt < 2; ++mt)
#pragma unroll
            for (int ntl = 0; ntl < 4; ++ntl)
                acc[mt][ntl] = (f32x4){0.f, 0.f, 0.f, 0.f};
#pragma unroll
        for (int ntl = 0; ntl < 4; ++ntl)
#pragma unroll
            for (int kt = 0; kt < 4; ++kt) {
                short8 b = bfr[(kt * 4 + ntl) * 64 + l];
                acc[0][ntl] = __builtin_amdgcn_mfma_f32_16x16x32_bf16(ahi[0][kt], b, acc[0][ntl], 0, 0, 0);
                acc[1][ntl] = __builtin_amdgcn_mfma_f32_16x16x32_bf16(ahi[1][kt], b, acc[1][ntl], 0, 0, 0);
            }

        // two 32-col chunks per pass
#pragma unroll
        for (int cn = 0; cn < 2; ++cn) {
            __syncthreads();   // b-reads (cn=0) / prev segmax reads (cn=1) done
#pragma unroll
            for (int nt2 = 0; nt2 < 2; ++nt2) {
                int ntl = 2 * cn + nt2;
#pragma unroll
                for (int mt = 0; mt < 2; ++mt)
#pragma unroll
                    for (int r = 0; r < 4; ++r)
                        M2[(32 * w + 16 * mt + 4 * q + r) * 34 + 16 * nt2 + m] = acc[mt][ntl][r];
            }
            __syncthreads();
            {
                int c = tid & 31, g = tid >> 5;
                int eb = 16 * g;
                int cur = sdst_s[eb];
                float mx = -3.402823466e38f;
                for (int e2 = eb; e2 < eb + 16; ++e2) {
                    int de = sdst_s[e2];
                    if (de != cur) {
                        atomicMax(&AGG[(size_t)cur * 128 + 64 * h + 32 * cn + c], enc_f32(mx));
                        cur = de;
                        mx = -3.402823466e38f;
                    }
                    mx = fmaxf(mx, M2[e2 * 34 + c]);
                }
                atomicMax(&AGG[(size_t)cur * 128 + 64 * h + 32 * cn + c], enc_f32(mx));
            }
        }
    }
}

// ---------------- launch ----------------

extern "C" void kernel_launch(void* const* d_in, const int* in_sizes, int n_in,
                              void* d_out, int out_size, void* d_ws, size_t ws_size,
                              hipStream_t stream) {
    const float* x   = (const float*)d_in[0];
    const int*   ei  = (const int*)d_in[1];
    const float* W1a = (const float*)d_in[2];
    const float* b1a = (const float*)d_in[3];
    const float* W1b = (const float*)d_in[4];
    const float* b1b = (const float*)d_in[5];
    const float* W2a = (const float*)d_in[6];
    const float* b2a = (const float*)d_in[7];
    const float* W2b = (const float*)d_in[8];
    const float* b2b = (const float*)d_in[9];
    const int* src = ei;
    const int* dst = ei + N_EDGES;

    char* ws = (char*)d_ws;
    unsigned short* UV    = (unsigned short*)ws;                 // 25.6 MB (bf16)
    unsigned*       AGG1  = (unsigned*)(ws + 25600000);          // 25.6 MB
    int*            ssrc  = (int*)(ws + 51200000);               // 3.2 MB
    int*            sdst  = (int*)(ws + 54400000);               // 3.2 MB
    unsigned*       count = (unsigned*)(ws + 57600000);          // 200 KB
    unsigned*       cursor= (unsigned*)(ws + 57800000);          // 200 KB
    unsigned short* Wg1   = (unsigned short*)(ws + 58000000);    // 32 KB (hi, half-major)
    unsigned short* Wg2   = (unsigned short*)(ws + 58065536);    // 32 KB
    unsigned short* WCg1  = (unsigned short*)(ws + 58327680);    // 64 KB (frag hi|lo)
    unsigned short* WCg2  = (unsigned short*)(ws + 58393216);    // 128 KB
    unsigned*       bsum  = (unsigned*)(ws + 58655744);          // 1 KB

    const int NH = N_NODES * HID;   // 6.4M

    // fused setup: W frags (WC computed inline) + AGG1/d_out/count fills
    setup<<<2048, 256, 0, stream>>>(W1a, W1b, W2a, W2b, Wg1, Wg2, WCg1, WCg2,
                                    AGG1, (unsigned*)d_out, count);

    // counting sort of edges by dst (max is order-independent -> deterministic)
    hist_dst<<<3125, 256, 0, stream>>>(dst, count);
    scan_p1<<<SCAN_B, 256, 0, stream>>>(count, bsum);
    scan_p2<<<1, 256, 0, stream>>>(bsum);
    scan_p3<<<SCAN_B, 256, 0, stream>>>(count, bsum, cursor);
    scatter_edges<<<3125, 256, 0, stream>>>(src, dst, cursor, ssrc, sdst);

    // Layer 1: UV = [x@(W1a_t - W1a_b) + b1a | x@W1a_b]  (bf16, U-bias folded)
    gemm_uv_mfma<0, 2><<<dim3(391, 2), 256, 0, stream>>>(x, WCg1, nullptr, b1a, UV, N_NODES);
    edge_mlp_mfma<<<NWG_E, 256, 0, stream>>>(UV, Wg1, ssrc, sdst, AGG1);

    // Layer 2: H = relu(dec(AGG1) + b1b) fused into A-load
    gemm_uv_mfma<1, 4><<<dim3(391, 2), 256, 0, stream>>>(AGG1, WCg2, b1b, b2a, UV, N_NODES);
    edge_mlp_mfma<<<NWG_E, 256, 0, stream>>>(UV, Wg2, ssrc, sdst, (unsigned*)d_out);
    out_decode<<<2048, 256, 0, stream>>>((unsigned*)d_out, b2b, NH);
}

// Round 10
// 309.073 us; speedup vs baseline: 1.0283x; 1.0187x over previous
//
#include <hip/hip_runtime.h>
#include <stdint.h>

#define N_NODES 50000
#define N_EDGES 800000
#define HID 128
#define NWG_E (N_EDGES / 128)      // 6250 edge blocks
#define XQ (NWG_E / 8)             // 781
#define XR (NWG_E % 8)             // 2
#define SCAN_B 196                 // 196*256 = 50176 >= N_NODES

#define ENC_NEG_INF 0x007FFFFFu   // enc(-inf)

typedef short short8 __attribute__((ext_vector_type(8)));
typedef float f32x4 __attribute__((ext_vector_type(4)));

__device__ __forceinline__ unsigned enc_f32(float f) {
    unsigned u = __float_as_uint(f);
    return (u & 0x80000000u) ? ~u : (u | 0x80000000u);
}
__device__ __forceinline__ float dec_f32(unsigned e) {
    unsigned u = (e & 0x80000000u) ? (e & 0x7FFFFFFFu) : ~e;
    return __uint_as_float(u);
}
__device__ __forceinline__ unsigned short f2bf(float f) {
    unsigned u = __float_as_uint(f);
    unsigned r = (u + 0x7fffu + ((u >> 16) & 1u)) >> 16;
    return (unsigned short)r;
}
__device__ __forceinline__ float bf2f(unsigned short h) {
    return __uint_as_float(((unsigned)h) << 16);
}
__device__ __forceinline__ float wcat_val(const float* __restrict__ W, int K, int k, int n) {
    // combined weight: cols 0..127 = Wtop - Wbot, 128..255 = Wbot
    return (n < 128) ? (W[k * 128 + n] - W[(k + K) * 128 + n]) : W[(k + K) * 128 + (n - 128)];
}

// ---------------- fused setup: W-frag preps + big fills ----------------
__global__ __launch_bounds__(256) void setup(
        const float* __restrict__ W1a, const float* __restrict__ W1b,
        const float* __restrict__ W2a, const float* __restrict__ W2b,
        unsigned short* __restrict__ Wg1, unsigned short* __restrict__ Wg2,
        unsigned short* __restrict__ WCg1, unsigned short* __restrict__ WCg2,
        unsigned* __restrict__ AGG1, unsigned* __restrict__ OUT,
        unsigned* __restrict__ count) {
    int bid = blockIdx.x, tid = threadIdx.x;
    const int NH = N_NODES * HID;

    if (bid < 128) {
        // Wg1/Wg2: Wb[128][128] -> hi-plane frags, HALF-MAJOR tile order
        const float* Wb = (bid < 64) ? W1b : W2b;
        unsigned short* Wg = (bid < 64) ? Wg1 : Wg2;
        int idx = (bid & 63) * 256 + tid;          // 0..16383
        int j = idx & 7, l = (idx >> 3) & 63, t = idx >> 9;
        int h = t >> 4, kt = (t >> 2) & 3, ntl = t & 3;
        int nt = 4 * h + ntl;
        int k = 32 * kt + 8 * (l >> 4) + j;
        int n = 16 * nt + (l & 15);
        Wg[idx] = f2bf(Wb[k * 128 + n]);
    } else if (bid < 192) {
        // WCg1: K=64, idx 0..16383, hi|lo planes
        int idx = (bid - 128) * 256 + tid;
        int j = idx & 7, l = (idx >> 3) & 63, nt = (idx >> 9) & 15, kt = idx >> 13;
        int k = 32 * kt + 8 * (l >> 4) + j;
        int n = 16 * nt + (l & 15);
        float v = wcat_val(W1a, 64, k, n);
        unsigned short hi = f2bf(v);
        WCg1[idx] = hi;
        WCg1[64 * 256 + idx] = f2bf(v - bf2f(hi));
    } else if (bid < 320) {
        // WCg2: K=128, idx 0..32767, hi|lo planes
        int idx = (bid - 192) * 256 + tid;
        int j = idx & 7, l = (idx >> 3) & 63, nt = (idx >> 9) & 15, kt = idx >> 13;
        int k = 32 * kt + 8 * (l >> 4) + j;
        int n = 16 * nt + (l & 15);
        float v = wcat_val(W2a, 128, k, n);
        unsigned short hi = f2bf(v);
        WCg2[idx] = hi;
        WCg2[128 * 256 + idx] = f2bf(v - bf2f(hi));
    }

    // fills: AGG1, OUT (= d_out), count
    int total = 2 * NH + N_NODES;
    for (int i = bid * 256 + tid; i < total; i += gridDim.x * 256) {
        if (i < NH) AGG1[i] = ENC_NEG_INF;
        else if (i < 2 * NH) OUT[i - NH] = ENC_NEG_INF;
        else count[i - 2 * NH] = 0u;
    }
}

// final: encoded u32 -> decoded float + bias; empty segment -> 0
__global__ void out_decode(unsigned* __restrict__ p, const float* __restrict__ bias, int n) {
    int i = blockIdx.x * blockDim.x + threadIdx.x;
    int stride = gridDim.x * blockDim.x;
    for (; i < n; i += stride) {
        unsigned e = p[i];
        float f = (e == ENC_NEG_INF) ? 0.0f : dec_f32(e) + bias[i & 127];
        ((float*)p)[i] = f;
    }
}

// ---------------- sort-by-dst (counting sort, multi-block scan) ----------------

__global__ void hist_dst(const int* __restrict__ dst, unsigned* __restrict__ count) {
    int i = blockIdx.x * blockDim.x + threadIdx.x;
    if (i < N_EDGES) atomicAdd(&count[dst[i]], 1u);
}

__global__ __launch_bounds__(256) void scan_p1(const unsigned* __restrict__ count,
                                               unsigned* __restrict__ bsum) {
    __shared__ unsigned s[256];
    int t = threadIdx.x;
    int i = blockIdx.x * 256 + t;
    s[t] = (i < N_NODES) ? count[i] : 0u;
    __syncthreads();
    for (int off = 128; off > 0; off >>= 1) {
        if (t < off) s[t] += s[t + off];
        __syncthreads();
    }
    if (t == 0) bsum[blockIdx.x] = s[0];
}

__global__ __launch_bounds__(256) void scan_p2(unsigned* __restrict__ bsum) {
    __shared__ unsigned s[256];
    int t = threadIdx.x;
    unsigned v = (t < SCAN_B) ? bsum[t] : 0u;
    s[t] = v;
    __syncthreads();
    for (int off = 1; off < 256; off <<= 1) {
        unsigned x = (t >= off) ? s[t - off] : 0u;
        __syncthreads();
        s[t] += x;
        __syncthreads();
    }
    if (t < SCAN_B) bsum[t] = s[t] - v;   // exclusive
}

__global__ __launch_bounds__(256) void scan_p3(const unsigned* __restrict__ count,
                                               const unsigned* __restrict__ bsum,
                                               unsigned* __restrict__ cursor) {
    __shared__ unsigned s[256];
    int t = threadIdx.x;
    int i = blockIdx.x * 256 + t;
    unsigned v = (i < N_NODES) ? count[i] : 0u;
    s[t] = v;
    __syncthreads();
    for (int off = 1; off < 256; off <<= 1) {
        unsigned x = (t >= off) ? s[t - off] : 0u;
        __syncthreads();
        s[t] += x;
        __syncthreads();
    }
    if (i < N_NODES) cursor[i] = bsum[blockIdx.x] + s[t] - v;
}

__global__ void scatter_edges(const int* __restrict__ src, const int* __restrict__ dst,
                              unsigned* __restrict__ cursor,
                              int* __restrict__ ssrc, int* __restrict__ sdst) {
    int i = blockIdx.x * blockDim.x + threadIdx.x;
    if (i < N_EDGES) {
        int d = dst[i];
        unsigned p = atomicAdd(&cursor[d], 1u);
        ssrc[p] = src[i];
        sdst[p] = d;
    }
}

// ---------------- MFMA node GEMM: C[M][256](bf16) = op(A)[M][K] @ WC[K][256] ----------------
template<int DEC, int KT>
__global__ __launch_bounds__(256, 2) void gemm_uv_mfma(
        const void* __restrict__ A_,
        const unsigned short* __restrict__ Wg,   // frag layout, hi|lo planes (K*256 shorts each)
        const float* __restrict__ bprev,         // DEC=1 bias (pre-relu); unused otherwise
        const float* __restrict__ bu,            // U-col bias, applied when by==0
        unsigned short* __restrict__ C,          // [M][256] bf16
        int M) {
    __shared__ char lds[KT * 8192];
    const int K = 32 * KT;
    int tid = threadIdx.x;
    int bx = blockIdx.x, by = blockIdx.y;
    int r0 = bx * 128;
    int w = tid >> 6, l = tid & 63;
    int q = l >> 4, m = l & 15;

    short8 ahi[2][KT];
#pragma unroll
    for (int mt = 0; mt < 2; ++mt) {
        int row = r0 + 32 * w + 16 * mt + m;
        bool ok = row < M;
#pragma unroll
        for (int kt = 0; kt < KT; ++kt) {
            float av[8] = {0.f, 0.f, 0.f, 0.f, 0.f, 0.f, 0.f, 0.f};
            if (ok) {
                if (DEC) {
                    const unsigned* Ar = (const unsigned*)A_ + (size_t)row * K + 32 * kt + 8 * q;
                    uint4 x0 = *(const uint4*)Ar;
                    uint4 x1 = *(const uint4*)(Ar + 4);
                    float4 g0 = *(const float4*)&bprev[32 * kt + 8 * q];
                    float4 g1 = *(const float4*)&bprev[32 * kt + 8 * q + 4];
                    av[0] = fmaxf(dec_f32(x0.x) + g0.x, 0.f);
                    av[1] = fmaxf(dec_f32(x0.y) + g0.y, 0.f);
                    av[2] = fmaxf(dec_f32(x0.z) + g0.z, 0.f);
                    av[3] = fmaxf(dec_f32(x0.w) + g0.w, 0.f);
                    av[4] = fmaxf(dec_f32(x1.x) + g1.x, 0.f);
                    av[5] = fmaxf(dec_f32(x1.y) + g1.y, 0.f);
                    av[6] = fmaxf(dec_f32(x1.z) + g1.z, 0.f);
                    av[7] = fmaxf(dec_f32(x1.w) + g1.w, 0.f);
                } else {
                    const float* Ar = (const float*)A_ + (size_t)row * K + 32 * kt + 8 * q;
                    float4 f0 = *(const float4*)Ar;
                    float4 f1 = *(const float4*)(Ar + 4);
                    av[0] = f0.x; av[1] = f0.y; av[2] = f0.z; av[3] = f0.w;
                    av[4] = f1.x; av[5] = f1.y; av[6] = f1.z; av[7] = f1.w;
                }
            }
            short8 hi;
#pragma unroll
            for (int j = 0; j < 8; ++j) hi[j] = (short)f2bf(av[j]);
            ahi[mt][kt] = hi;
        }
    }

    f32x4 acc[2][8];
#pragma unroll
    for (int mt = 0; mt < 2; ++mt)
#pragma unroll
        for (int nt = 0; nt < 8; ++nt)
            acc[mt][nt] = (f32x4){0.f, 0.f, 0.f, 0.f};

    const short8* bfr = (const short8*)lds;

#pragma unroll
    for (int pl = 0; pl < 2; ++pl) {
        if (pl) __syncthreads();
        {
            const float4* s4 = (const float4*)Wg + (size_t)pl * (K * 32);
            float4* d4 = (float4*)lds;
#pragma unroll
            for (int it = 0; it < 2 * KT; ++it) {
                int f = 256 * it + tid;
                int tl = f >> 6, fin = f & 63;
                int tg = (tl >> 3) * 16 + 8 * by + (tl & 7);
                d4[f] = s4[tg * 64 + fin];
            }
        }
        __syncthreads();
#pragma unroll
        for (int nt = 0; nt < 8; ++nt)
#pragma unroll
            for (int kt = 0; kt < KT; ++kt) {
                short8 b = bfr[(kt * 8 + nt) * 64 + l];
                acc[0][nt] = __builtin_amdgcn_mfma_f32_16x16x32_bf16(ahi[0][kt], b, acc[0][nt], 0, 0, 0);
                acc[1][nt] = __builtin_amdgcn_mfma_f32_16x16x32_bf16(ahi[1][kt], b, acc[1][nt], 0, 0, 0);
            }
    }

#pragma unroll
    for (int nt = 0; nt < 8; ++nt) {
        float bias = (by == 0) ? bu[16 * nt + m] : 0.f;
#pragma unroll
        for (int mt = 0; mt < 2; ++mt) {
            int rowb = r0 + 32 * w + 16 * mt + 4 * q;
#pragma unroll
            for (int r = 0; r < 4; ++r) {
                int row = rowb + r;
                if (row < M)
                    C[(size_t)row * 256 + 128 * by + 16 * nt + m] = f2bf(acc[mt][nt][r] + bias);
            }
        }
    }
}

// ---------------- MFMA edge MLP + segmented max-aggregate ----------------
// 128 sorted edges / block, 4 waves. SINGLE barrier (after W stage); the reduce
// uses wave-private M2 LDS slices so all later phases are barrier-free.
__global__ __launch_bounds__(256, 3) void edge_mlp_mfma(
        const unsigned short* __restrict__ UV, // [N][256] bf16: U 0..127 (incl. ba), V 128..255
        const unsigned short* __restrict__ Wg, // hi plane, half-major tiles (16384 shorts)
        const int* __restrict__ ssrc,
        const int* __restrict__ sdst,
        unsigned* __restrict__ AGG) {          // [N][128] encoded (bb added downstream)
    __shared__ char lds[32768 + 4 * 4352];     // W (32KB) + per-wave M2[32][34] f32
    int tid = threadIdx.x;
    // bijective XCD-chunked swizzle
    int orig = blockIdx.x;
    int xcd = orig & 7, ii = orig >> 3;
    int wg = (xcd < XR) ? xcd * (XQ + 1) + ii : XR * (XQ + 1) + (xcd - XR) * XQ + ii;
    int e0 = wg * 128;
    int w = tid >> 6, l = tid & 63;
    int q = l >> 4, m = l & 15;

    // A-gather: issue all loads
    short8 ub[2][4], vb[2][4];
    {
        int eA = e0 + 32 * w + m;
        int d0 = sdst[eA], s0 = ssrc[eA];
        int d1 = sdst[eA + 16], s1 = ssrc[eA + 16];
        const short8* Ud0 = (const short8*)&UV[(size_t)d0 * 256];
        const short8* Vs0 = (const short8*)&UV[(size_t)s0 * 256 + 128];
        const short8* Ud1 = (const short8*)&UV[(size_t)d1 * 256];
        const short8* Vs1 = (const short8*)&UV[(size_t)s1 * 256 + 128];
#pragma unroll
        for (int kt = 0; kt < 4; ++kt) {
            ub[0][kt] = Ud0[4 * kt + q];
            vb[0][kt] = Vs0[4 * kt + q];
            ub[1][kt] = Ud1[4 * kt + q];
            vb[1][kt] = Vs1[4 * kt + q];
        }
    }

    // seg-max window dst values for this lane (16 ints, register-resident)
    int4 dw[4];
    {
        const int4* dsrc = (const int4*)&sdst[e0 + 32 * w + 16 * (l >> 5)];
        dw[0] = dsrc[0]; dw[1] = dsrc[1]; dw[2] = dsrc[2]; dw[3] = dsrc[3];
    }

    // cooperative W stage: full 32KB hi plane
    {
        const float4* s4 = (const float4*)Wg;
        float4* d4 = (float4*)lds;
#pragma unroll
        for (int i = 0; i < 8; ++i) d4[tid + 256 * i] = s4[tid + 256 * i];
    }

    // convert A to bf16 (VALU, overlaps other waves' memory)
    short8 ahi[2][4];
#pragma unroll
    for (int mt = 0; mt < 2; ++mt)
#pragma unroll
        for (int kt = 0; kt < 4; ++kt) {
            short8 hi;
#pragma unroll
            for (int j = 0; j < 8; ++j) {
                float t = bf2f((unsigned short)ub[mt][kt][j]) + bf2f((unsigned short)vb[mt][kt][j]);
                hi[j] = (short)f2bf(fmaxf(t, 0.f));
            }
            ahi[mt][kt] = hi;
        }

    __syncthreads();   // W visible — the ONLY barrier

    const short8* bfr = (const short8*)lds;
    float* M2 = (float*)(lds + 32768 + w * 4352);   // wave-private [32][34] f32
    f32x4 acc[2][4];

#pragma unroll
    for (int h = 0; h < 2; ++h) {
#pragma unroll
        for (int mt = 0; mt < 2; ++mt)
#pragma unroll
            for (int ntl = 0; ntl < 4; ++ntl)
                acc[mt][ntl] = (f32x4){0.f, 0.f, 0.f, 0.f};
#pragma unroll
        for (int ntl = 0; ntl < 4; ++ntl)
#pragma unroll
            for (int kt = 0; kt < 4; ++kt) {
                short8 b = bfr[(h * 16 + kt * 4 + ntl) * 64 + l];
                acc[0][ntl] = __builtin_amdgcn_mfma_f32_16x16x32_bf16(ahi[0][kt], b, acc[0][ntl], 0, 0, 0);
                acc[1][ntl] = __builtin_amdgcn_mfma_f32_16x16x32_bf16(ahi[1][kt], b, acc[1][ntl], 0, 0, 0);
            }

        // two 32-col chunks; wave-private M2, no barriers (same-wave lgkmcnt ordering)
#pragma unroll
        for (int cn = 0; cn < 2; ++cn) {
#pragma unroll
            for (int nt2 = 0; nt2 < 2; ++nt2) {
                int ntl = 2 * cn + nt2;
#pragma unroll
                for (int mt = 0; mt < 2; ++mt)
#pragma unroll
                    for (int r = 0; r < 4; ++r)
                        M2[(16 * mt + 4 * q + r) * 34 + 16 * nt2 + m] = acc[mt][ntl][r];
            }
            {
                int c = l & 31;
                const int* dwp = (const int*)dw;
                int cur = dwp[0];
                float mx = -3.402823466e38f;
#pragma unroll
                for (int i = 0; i < 16; ++i) {
                    int de = dwp[i];
                    if (de != cur) {
                        atomicMax(&AGG[(size_t)cur * 128 + 64 * h + 32 * cn + c], enc_f32(mx));
                        cur = de;
                        mx = -3.402823466e38f;
                    }
                    mx = fmaxf(mx, M2[(16 * (l >> 5) + i) * 34 + c]);
                }
                atomicMax(&AGG[(size_t)cur * 128 + 64 * h + 32 * cn + c], enc_f32(mx));
            }
        }
    }
}

// ---------------- launch ----------------

extern "C" void kernel_launch(void* const* d_in, const int* in_sizes, int n_in,
                              void* d_out, int out_size, void* d_ws, size_t ws_size,
                              hipStream_t stream) {
    const float* x   = (const float*)d_in[0];
    const int*   ei  = (const int*)d_in[1];
    const float* W1a = (const float*)d_in[2];
    const float* b1a = (const float*)d_in[3];
    const float* W1b = (const float*)d_in[4];
    const float* b1b = (const float*)d_in[5];
    const float* W2a = (const float*)d_in[6];
    const float* b2a = (const float*)d_in[7];
    const float* W2b = (const float*)d_in[8];
    const float* b2b = (const float*)d_in[9];
    const int* src = ei;
    const int* dst = ei + N_EDGES;

    char* ws = (char*)d_ws;
    unsigned short* UV    = (unsigned short*)ws;                 // 25.6 MB (bf16)
    unsigned*       AGG1  = (unsigned*)(ws + 25600000);          // 25.6 MB
    int*            ssrc  = (int*)(ws + 51200000);               // 3.2 MB
    int*            sdst  = (int*)(ws + 54400000);               // 3.2 MB
    unsigned*       count = (unsigned*)(ws + 57600000);          // 200 KB
    unsigned*       cursor= (unsigned*)(ws + 57800000);          // 200 KB
    unsigned short* Wg1   = (unsigned short*)(ws + 58000000);    // 32 KB (hi, half-major)
    unsigned short* Wg2   = (unsigned short*)(ws + 58065536);    // 32 KB
    unsigned short* WCg1  = (unsigned short*)(ws + 58327680);    // 64 KB (frag hi|lo)
    unsigned short* WCg2  = (unsigned short*)(ws + 58393216);    // 128 KB
    unsigned*       bsum  = (unsigned*)(ws + 58655744);          // 1 KB

    const int NH = N_NODES * HID;   // 6.4M

    // fused setup: W frags (WC computed inline) + AGG1/d_out/count fills
    setup<<<2048, 256, 0, stream>>>(W1a, W1b, W2a, W2b, Wg1, Wg2, WCg1, WCg2,
                                    AGG1, (unsigned*)d_out, count);

    // counting sort of edges by dst (max is order-independent -> deterministic)
    hist_dst<<<3125, 256, 0, stream>>>(dst, count);
    scan_p1<<<SCAN_B, 256, 0, stream>>>(count, bsum);
    scan_p2<<<1, 256, 0, stream>>>(bsum);
    scan_p3<<<SCAN_B, 256, 0, stream>>>(count, bsum, cursor);
    scatter_edges<<<3125, 256, 0, stream>>>(src, dst, cursor, ssrc, sdst);

    // Layer 1: UV = [x@(W1a_t - W1a_b) + b1a | x@W1a_b]  (bf16, U-bias folded)
    gemm_uv_mfma<0, 2><<<dim3(391, 2), 256, 0, stream>>>(x, WCg1, nullptr, b1a, UV, N_NODES);
    edge_mlp_mfma<<<NWG_E, 256, 0, stream>>>(UV, Wg1, ssrc, sdst, AGG1);

    // Layer 2: H = relu(dec(AGG1) + b1b) fused into A-load
    gemm_uv_mfma<1, 4><<<dim3(391, 2), 256, 0, stream>>>(AGG1, WCg2, b1b, b2a, UV, N_NODES);
    edge_mlp_mfma<<<NWG_E, 256, 0, stream>>>(UV, Wg2, ssrc, sdst, (unsigned*)d_out);
    out_decode<<<2048, 256, 0, stream>>>((unsigned*)d_out, b2b, NH);
}

// Round 11
// 292.304 us; speedup vs baseline: 1.0873x; 1.0574x over previous
//
#include <hip/hip_runtime.h>
#include <stdint.h>

#define N_NODES 50000
#define N_EDGES 800000
#define HID 128
#define NWG_E (N_EDGES / 128)      // 6250 edge blocks
#define XQ (NWG_E / 8)             // 781
#define XR (NWG_E % 8)             // 2
#define SCAN_B 196                 // 196*256 = 50176 >= N_NODES

#define ENC_NEG_INF 0x007FFFFFu   // enc(-inf)

typedef short short8 __attribute__((ext_vector_type(8)));
typedef float f32x4 __attribute__((ext_vector_type(4)));

__device__ __forceinline__ unsigned enc_f32(float f) {
    unsigned u = __float_as_uint(f);
    return (u & 0x80000000u) ? ~u : (u | 0x80000000u);
}
__device__ __forceinline__ float dec_f32(unsigned e) {
    unsigned u = (e & 0x80000000u) ? (e & 0x7FFFFFFFu) : ~e;
    return __uint_as_float(u);
}
__device__ __forceinline__ unsigned short f2bf(float f) {
    unsigned u = __float_as_uint(f);
    unsigned r = (u + 0x7fffu + ((u >> 16) & 1u)) >> 16;
    return (unsigned short)r;
}
__device__ __forceinline__ float bf2f(unsigned short h) {
    return __uint_as_float(((unsigned)h) << 16);
}
__device__ __forceinline__ float wcat_val(const float* __restrict__ W, int K, int k, int n) {
    // combined weight: cols 0..127 = Wtop - Wbot, 128..255 = Wbot
    return (n < 128) ? (W[k * 128 + n] - W[(k + K) * 128 + n]) : W[(k + K) * 128 + (n - 128)];
}

// ---------------- fused setup: W-frag preps (hi planes only) + big fills ----------------
__global__ __launch_bounds__(256) void setup(
        const float* __restrict__ W1a, const float* __restrict__ W1b,
        const float* __restrict__ W2a, const float* __restrict__ W2b,
        unsigned short* __restrict__ Wg1, unsigned short* __restrict__ Wg2,
        unsigned short* __restrict__ WCg1, unsigned short* __restrict__ WCg2,
        unsigned* __restrict__ AGG1, unsigned* __restrict__ OUT,
        unsigned* __restrict__ count) {
    int bid = blockIdx.x, tid = threadIdx.x;
    const int NH = N_NODES * HID;

    if (bid < 128) {
        // Wg1/Wg2: Wb[128][128] -> hi-plane frags, HALF-MAJOR tile order
        const float* Wb = (bid < 64) ? W1b : W2b;
        unsigned short* Wg = (bid < 64) ? Wg1 : Wg2;
        int idx = (bid & 63) * 256 + tid;          // 0..16383
        int j = idx & 7, l = (idx >> 3) & 63, t = idx >> 9;
        int h = t >> 4, kt = (t >> 2) & 3, ntl = t & 3;
        int nt = 4 * h + ntl;
        int k = 32 * kt + 8 * (l >> 4) + j;
        int n = 16 * nt + (l & 15);
        Wg[idx] = f2bf(Wb[k * 128 + n]);
    } else if (bid < 192) {
        // WCg1: K=64, idx 0..16383, hi plane only
        int idx = (bid - 128) * 256 + tid;
        int j = idx & 7, l = (idx >> 3) & 63, nt = (idx >> 9) & 15, kt = idx >> 13;
        int k = 32 * kt + 8 * (l >> 4) + j;
        int n = 16 * nt + (l & 15);
        WCg1[idx] = f2bf(wcat_val(W1a, 64, k, n));
    } else if (bid < 320) {
        // WCg2: K=128, idx 0..32767, hi plane only
        int idx = (bid - 192) * 256 + tid;
        int j = idx & 7, l = (idx >> 3) & 63, nt = (idx >> 9) & 15, kt = idx >> 13;
        int k = 32 * kt + 8 * (l >> 4) + j;
        int n = 16 * nt + (l & 15);
        WCg2[idx] = f2bf(wcat_val(W2a, 128, k, n));
    }

    // fills: AGG1, OUT (= d_out), count
    int total = 2 * NH + N_NODES;
    for (int i = bid * 256 + tid; i < total; i += gridDim.x * 256) {
        if (i < NH) AGG1[i] = ENC_NEG_INF;
        else if (i < 2 * NH) OUT[i - NH] = ENC_NEG_INF;
        else count[i - 2 * NH] = 0u;
    }
}

// final: encoded u32 -> decoded float + bias; empty segment -> 0
__global__ void out_decode(unsigned* __restrict__ p, const float* __restrict__ bias, int n) {
    int i = blockIdx.x * blockDim.x + threadIdx.x;
    int stride = gridDim.x * blockDim.x;
    for (; i < n; i += stride) {
        unsigned e = p[i];
        float f = (e == ENC_NEG_INF) ? 0.0f : dec_f32(e) + bias[i & 127];
        ((float*)p)[i] = f;
    }
}

// ---------------- sort-by-dst (counting sort, multi-block scan) ----------------

__global__ void hist_dst(const int* __restrict__ dst, unsigned* __restrict__ count) {
    int i = blockIdx.x * blockDim.x + threadIdx.x;
    if (i < N_EDGES) atomicAdd(&count[dst[i]], 1u);
}

__global__ __launch_bounds__(256) void scan_p1(const unsigned* __restrict__ count,
                                               unsigned* __restrict__ bsum) {
    __shared__ unsigned s[256];
    int t = threadIdx.x;
    int i = blockIdx.x * 256 + t;
    s[t] = (i < N_NODES) ? count[i] : 0u;
    __syncthreads();
    for (int off = 128; off > 0; off >>= 1) {
        if (t < off) s[t] += s[t + off];
        __syncthreads();
    }
    if (t == 0) bsum[blockIdx.x] = s[0];
}

__global__ __launch_bounds__(256) void scan_p2(unsigned* __restrict__ bsum) {
    __shared__ unsigned s[256];
    int t = threadIdx.x;
    unsigned v = (t < SCAN_B) ? bsum[t] : 0u;
    s[t] = v;
    __syncthreads();
    for (int off = 1; off < 256; off <<= 1) {
        unsigned x = (t >= off) ? s[t - off] : 0u;
        __syncthreads();
        s[t] += x;
        __syncthreads();
    }
    if (t < SCAN_B) bsum[t] = s[t] - v;   // exclusive
}

__global__ __launch_bounds__(256) void scan_p3(const unsigned* __restrict__ count,
                                               const unsigned* __restrict__ bsum,
                                               unsigned* __restrict__ cursor) {
    __shared__ unsigned s[256];
    int t = threadIdx.x;
    int i = blockIdx.x * 256 + t;
    unsigned v = (i < N_NODES) ? count[i] : 0u;
    s[t] = v;
    __syncthreads();
    for (int off = 1; off < 256; off <<= 1) {
        unsigned x = (t >= off) ? s[t - off] : 0u;
        __syncthreads();
        s[t] += x;
        __syncthreads();
    }
    if (i < N_NODES) cursor[i] = bsum[blockIdx.x] + s[t] - v;
}

__global__ void scatter_edges(const int* __restrict__ src, const int* __restrict__ dst,
                              unsigned* __restrict__ cursor,
                              int* __restrict__ ssrc, int* __restrict__ sdst) {
    int i = blockIdx.x * blockDim.x + threadIdx.x;
    if (i < N_EDGES) {
        int d = dst[i];
        unsigned p = atomicAdd(&cursor[d], 1u);
        ssrc[p] = src[i];
        sdst[p] = d;
    }
}

// ---------------- MFMA node GEMM: C[M][256](bf16) = op(A)[M][K] @ WC_hi[K][256] ----------------
template<int DEC, int KT>
__global__ __launch_bounds__(256, 3) void gemm_uv_mfma(
        const void* __restrict__ A_,
        const unsigned short* __restrict__ Wg,   // frag layout, hi plane (K*256 shorts)
        const float* __restrict__ bprev,         // DEC=1 bias (pre-relu); unused otherwise
        const float* __restrict__ bu,            // U-col bias, applied when by==0
        unsigned short* __restrict__ C,          // [M][256] bf16
        int M) {
    __shared__ char lds[KT * 8192];
    const int K = 32 * KT;
    int tid = threadIdx.x;
    int bx = blockIdx.x, by = blockIdx.y;
    int r0 = bx * 128;
    int w = tid >> 6, l = tid & 63;
    int q = l >> 4, m = l & 15;

    short8 ahi[2][KT];
#pragma unroll
    for (int mt = 0; mt < 2; ++mt) {
        int row = r0 + 32 * w + 16 * mt + m;
        bool ok = row < M;
#pragma unroll
        for (int kt = 0; kt < KT; ++kt) {
            float av[8] = {0.f, 0.f, 0.f, 0.f, 0.f, 0.f, 0.f, 0.f};
            if (ok) {
                if (DEC) {
                    const unsigned* Ar = (const unsigned*)A_ + (size_t)row * K + 32 * kt + 8 * q;
                    uint4 x0 = *(const uint4*)Ar;
                    uint4 x1 = *(const uint4*)(Ar + 4);
                    float4 g0 = *(const float4*)&bprev[32 * kt + 8 * q];
                    float4 g1 = *(const float4*)&bprev[32 * kt + 8 * q + 4];
                    av[0] = fmaxf(dec_f32(x0.x) + g0.x, 0.f);
                    av[1] = fmaxf(dec_f32(x0.y) + g0.y, 0.f);
                    av[2] = fmaxf(dec_f32(x0.z) + g0.z, 0.f);
                    av[3] = fmaxf(dec_f32(x0.w) + g0.w, 0.f);
                    av[4] = fmaxf(dec_f32(x1.x) + g1.x, 0.f);
                    av[5] = fmaxf(dec_f32(x1.y) + g1.y, 0.f);
                    av[6] = fmaxf(dec_f32(x1.z) + g1.z, 0.f);
                    av[7] = fmaxf(dec_f32(x1.w) + g1.w, 0.f);
                } else {
                    const float* Ar = (const float*)A_ + (size_t)row * K + 32 * kt + 8 * q;
                    float4 f0 = *(const float4*)Ar;
                    float4 f1 = *(const float4*)(Ar + 4);
                    av[0] = f0.x; av[1] = f0.y; av[2] = f0.z; av[3] = f0.w;
                    av[4] = f1.x; av[5] = f1.y; av[6] = f1.z; av[7] = f1.w;
                }
            }
            short8 hi;
#pragma unroll
            for (int j = 0; j < 8; ++j) hi[j] = (short)f2bf(av[j]);
            ahi[mt][kt] = hi;
        }
    }

    f32x4 acc[2][8];
#pragma unroll
    for (int mt = 0; mt < 2; ++mt)
#pragma unroll
        for (int nt = 0; nt < 8; ++nt)
            acc[mt][nt] = (f32x4){0.f, 0.f, 0.f, 0.f};

    const short8* bfr = (const short8*)lds;

    // stage hi plane portion for this by
    {
        const float4* s4 = (const float4*)Wg;
        float4* d4 = (float4*)lds;
#pragma unroll
        for (int it = 0; it < 2 * KT; ++it) {
            int f = 256 * it + tid;
            int tl = f >> 6, fin = f & 63;
            int tg = (tl >> 3) * 16 + 8 * by + (tl & 7);
            d4[f] = s4[tg * 64 + fin];
        }
    }
    __syncthreads();
#pragma unroll
    for (int nt = 0; nt < 8; ++nt)
#pragma unroll
        for (int kt = 0; kt < KT; ++kt) {
            short8 b = bfr[(kt * 8 + nt) * 64 + l];
            acc[0][nt] = __builtin_amdgcn_mfma_f32_16x16x32_bf16(ahi[0][kt], b, acc[0][nt], 0, 0, 0);
            acc[1][nt] = __builtin_amdgcn_mfma_f32_16x16x32_bf16(ahi[1][kt], b, acc[1][nt], 0, 0, 0);
        }

#pragma unroll
    for (int nt = 0; nt < 8; ++nt) {
        float bias = (by == 0) ? bu[16 * nt + m] : 0.f;
#pragma unroll
        for (int mt = 0; mt < 2; ++mt) {
            int rowb = r0 + 32 * w + 16 * mt + 4 * q;
#pragma unroll
            for (int r = 0; r < 4; ++r) {
                int row = rowb + r;
                if (row < M)
                    C[(size_t)row * 256 + 128 * by + 16 * nt + m] = f2bf(acc[mt][nt][r] + bias);
            }
        }
    }
}

// ---------------- MFMA edge MLP + segmented max-aggregate ----------------
// 128 sorted edges / block, 4 waves, 4 blocks/CU. W staged in 16KB halves
// (3 barriers); reduce is wave-private LDS, overlapped with the h1 W-stage.
__global__ __launch_bounds__(256, 4) void edge_mlp_mfma(
        const unsigned short* __restrict__ UV, // [N][256] bf16: U 0..127 (incl. ba), V 128..255
        const unsigned short* __restrict__ Wg, // hi plane, half-major tiles (16384 shorts)
        const int* __restrict__ ssrc,
        const int* __restrict__ sdst,
        unsigned* __restrict__ AGG) {          // [N][128] encoded (bb added downstream)
    __shared__ char lds[16384 + 4 * 4352];     // W half (16KB) + per-wave M2[32][34] f32
    int tid = threadIdx.x;
    // bijective XCD-chunked swizzle
    int orig = blockIdx.x;
    int xcd = orig & 7, ii = orig >> 3;
    int wg = (xcd < XR) ? xcd * (XQ + 1) + ii : XR * (XQ + 1) + (xcd - XR) * XQ + ii;
    int e0 = wg * 128;
    int w = tid >> 6, l = tid & 63;
    int q = l >> 4, m = l & 15;

    // A-gather: issue all loads
    short8 ub[2][4], vb[2][4];
    {
        int eA = e0 + 32 * w + m;
        int d0 = sdst[eA], s0 = ssrc[eA];
        int d1 = sdst[eA + 16], s1 = ssrc[eA + 16];
        const short8* Ud0 = (const short8*)&UV[(size_t)d0 * 256];
        const short8* Vs0 = (const short8*)&UV[(size_t)s0 * 256 + 128];
        const short8* Ud1 = (const short8*)&UV[(size_t)d1 * 256];
        const short8* Vs1 = (const short8*)&UV[(size_t)s1 * 256 + 128];
#pragma unroll
        for (int kt = 0; kt < 4; ++kt) {
            ub[0][kt] = Ud0[4 * kt + q];
            vb[0][kt] = Vs0[4 * kt + q];
            ub[1][kt] = Ud1[4 * kt + q];
            vb[1][kt] = Vs1[4 * kt + q];
        }
    }

    // seg-max window dst values for this lane (16 ints, register-resident)
    int4 dw[4];
    {
        const int4* dsrc = (const int4*)&sdst[e0 + 32 * w + 16 * (l >> 5)];
        dw[0] = dsrc[0]; dw[1] = dsrc[1]; dw[2] = dsrc[2]; dw[3] = dsrc[3];
    }

    // stage W half 0 (16KB)
    {
        const float4* s4 = (const float4*)Wg;
        float4* d4 = (float4*)lds;
#pragma unroll
        for (int i = 0; i < 4; ++i) d4[tid + 256 * i] = s4[tid + 256 * i];
    }

    // convert A to bf16 (VALU, overlaps loads' latency)
    short8 ahi[2][4];
#pragma unroll
    for (int mt = 0; mt < 2; ++mt)
#pragma unroll
        for (int kt = 0; kt < 4; ++kt) {
            short8 hi;
#pragma unroll
            for (int j = 0; j < 8; ++j) {
                float t = bf2f((unsigned short)ub[mt][kt][j]) + bf2f((unsigned short)vb[mt][kt][j]);
                hi[j] = (short)f2bf(fmaxf(t, 0.f));
            }
            ahi[mt][kt] = hi;
        }

    __syncthreads();   // W half 0 visible

    const short8* bfr = (const short8*)lds;
    float* M2 = (float*)(lds + 16384 + w * 4352);   // wave-private [32][34] f32
    f32x4 acc[2][4];

#pragma unroll
    for (int h = 0; h < 2; ++h) {
#pragma unroll
        for (int mt = 0; mt < 2; ++mt)
#pragma unroll
            for (int ntl = 0; ntl < 4; ++ntl)
                acc[mt][ntl] = (f32x4){0.f, 0.f, 0.f, 0.f};
#pragma unroll
        for (int ntl = 0; ntl < 4; ++ntl)
#pragma unroll
            for (int kt = 0; kt < 4; ++kt) {
                short8 b = bfr[(kt * 4 + ntl) * 64 + l];
                acc[0][ntl] = __builtin_amdgcn_mfma_f32_16x16x32_bf16(ahi[0][kt], b, acc[0][ntl], 0, 0, 0);
                acc[1][ntl] = __builtin_amdgcn_mfma_f32_16x16x32_bf16(ahi[1][kt], b, acc[1][ntl], 0, 0, 0);
            }

        if (h == 0) {
            __syncthreads();   // everyone done reading W half 0
            // stage W half 1 (overlaps with the reduce below)
            const float4* s4 = (const float4*)Wg + 1024;
            float4* d4 = (float4*)lds;
#pragma unroll
            for (int i = 0; i < 4; ++i) d4[tid + 256 * i] = s4[tid + 256 * i];
        }

        // two 32-col chunks; wave-private M2, no barriers (same-wave lgkmcnt ordering)
#pragma unroll
        for (int cn = 0; cn < 2; ++cn) {
#pragma unroll
            for (int nt2 = 0; nt2 < 2; ++nt2) {
                int ntl = 2 * cn + nt2;
#pragma unroll
                for (int mt = 0; mt < 2; ++mt)
#pragma unroll
                    for (int r = 0; r < 4; ++r)
                        M2[(16 * mt + 4 * q + r) * 34 + 16 * nt2 + m] = acc[mt][ntl][r];
            }
            {
                int c = l & 31;
                const int* dwp = (const int*)dw;
                int cur = dwp[0];
                float mx = -3.402823466e38f;
#pragma unroll
                for (int i = 0; i < 16; ++i) {
                    int de = dwp[i];
                    if (de != cur) {
                        atomicMax(&AGG[(size_t)cur * 128 + 64 * h + 32 * cn + c], enc_f32(mx));
                        cur = de;
                        mx = -3.402823466e38f;
                    }
                    mx = fmaxf(mx, M2[(16 * (l >> 5) + i) * 34 + c]);
                }
                atomicMax(&AGG[(size_t)cur * 128 + 64 * h + 32 * cn + c], enc_f32(mx));
            }
        }

        if (h == 0) __syncthreads();   // W half 1 visible
    }
}

// ---------------- launch ----------------

extern "C" void kernel_launch(void* const* d_in, const int* in_sizes, int n_in,
                              void* d_out, int out_size, void* d_ws, size_t ws_size,
                              hipStream_t stream) {
    const float* x   = (const float*)d_in[0];
    const int*   ei  = (const int*)d_in[1];
    const float* W1a = (const float*)d_in[2];
    const float* b1a = (const float*)d_in[3];
    const float* W1b = (const float*)d_in[4];
    const float* b1b = (const float*)d_in[5];
    const float* W2a = (const float*)d_in[6];
    const float* b2a = (const float*)d_in[7];
    const float* W2b = (const float*)d_in[8];
    const float* b2b = (const float*)d_in[9];
    const int* src = ei;
    const int* dst = ei + N_EDGES;

    char* ws = (char*)d_ws;
    unsigned short* UV    = (unsigned short*)ws;                 // 25.6 MB (bf16)
    unsigned*       AGG1  = (unsigned*)(ws + 25600000);          // 25.6 MB
    int*            ssrc  = (int*)(ws + 51200000);               // 3.2 MB
    int*            sdst  = (int*)(ws + 54400000);               // 3.2 MB
    unsigned*       count = (unsigned*)(ws + 57600000);          // 200 KB
    unsigned*       cursor= (unsigned*)(ws + 57800000);          // 200 KB
    unsigned short* Wg1   = (unsigned short*)(ws + 58000000);    // 32 KB (hi, half-major)
    unsigned short* Wg2   = (unsigned short*)(ws + 58065536);    // 32 KB
    unsigned short* WCg1  = (unsigned short*)(ws + 58327680);    // 32 KB (hi)
    unsigned short* WCg2  = (unsigned short*)(ws + 58393216);    // 64 KB (hi)
    unsigned*       bsum  = (unsigned*)(ws + 58655744);          // 1 KB

    const int NH = N_NODES * HID;   // 6.4M

    // fused setup: W frags (hi planes, WC computed inline) + AGG1/d_out/count fills
    setup<<<2048, 256, 0, stream>>>(W1a, W1b, W2a, W2b, Wg1, Wg2, WCg1, WCg2,
                                    AGG1, (unsigned*)d_out, count);

    // counting sort of edges by dst (max is order-independent -> deterministic)
    hist_dst<<<3125, 256, 0, stream>>>(dst, count);
    scan_p1<<<SCAN_B, 256, 0, stream>>>(count, bsum);
    scan_p2<<<1, 256, 0, stream>>>(bsum);
    scan_p3<<<SCAN_B, 256, 0, stream>>>(count, bsum, cursor);
    scatter_edges<<<3125, 256, 0, stream>>>(src, dst, cursor, ssrc, sdst);

    // Layer 1: UV = [x@(W1a_t - W1a_b) + b1a | x@W1a_b]  (bf16, U-bias folded)
    gemm_uv_mfma<0, 2><<<dim3(391, 2), 256, 0, stream>>>(x, WCg1, nullptr, b1a, UV, N_NODES);
    edge_mlp_mfma<<<NWG_E, 256, 0, stream>>>(UV, Wg1, ssrc, sdst, AGG1);

    // Layer 2: H = relu(dec(AGG1) + b1b) fused into A-load
    gemm_uv_mfma<1, 4><<<dim3(391, 2), 256, 0, stream>>>(AGG1, WCg2, b1b, b2a, UV, N_NODES);
    edge_mlp_mfma<<<NWG_E, 256, 0, stream>>>(UV, Wg2, ssrc, sdst, (unsigned*)d_out);
    out_decode<<<2048, 256, 0, stream>>>((unsigned*)d_out, b2b, NH);
}